// Round 16
// baseline (362.926 us; speedup 1.0000x reference)
//
#include <hip/hip_runtime.h>

#define NNODES 50000
#define NEDGES 800000
#define NF 96
#define NF4 24              // float4 per f32 row
#define NBW 4               // nodes per wave (fused): 12500 waves total
#define WPB 4               // waves per block (256 threads); block owns 16 nodes
#define ACC_STRIDE 100      // Acc/T/Ht row stride (floats, 400B, 16B-aligned)

typedef short bf16x8 __attribute__((ext_vector_type(8)));
typedef float f32x4 __attribute__((ext_vector_type(4)));

__device__ inline unsigned pk_bf16(float a, float b) {
    union { __bf16 h[2]; unsigned u; } q;
    q.h[0] = (__bf16)a; q.h[1] = (__bf16)b;
    return q.u;
}
__device__ inline unsigned short bf16_1(float a) {
    union { __bf16 h; unsigned short u; } q;
    q.h = (__bf16)a;
    return q.u;
}
__device__ inline bf16x8 cvt8(float4 a, float4 b) {
    union { unsigned u[4]; bf16x8 v; } q;
    q.u[0] = pk_bf16(a.x, a.y); q.u[1] = pk_bf16(a.z, a.w);
    q.u[2] = pk_bf16(b.x, b.y); q.u[3] = pk_bf16(b.z, b.w);
    return q.v;
}
__device__ inline int imin(int a, int b) { return a < b ? a : b; }

// ---------------------------------------------------------------------------
// prep: blocks 0/1/2 pack We/W1/W2 into MFMA B-fragment order (bf16);
// remaining blocks do the dst histogram.
// ---------------------------------------------------------------------------
__global__ __launch_bounds__(256) void prep_hist(
    const float* __restrict__ We, const float* __restrict__ W1,
    const float* __restrict__ W2, unsigned short* __restrict__ Wep,
    unsigned short* __restrict__ W1p, unsigned short* __restrict__ W2p,
    const int* __restrict__ ei, int* __restrict__ deg) {
    int b = blockIdx.x;
    if (b < 3) {
        const float* S = (b == 0) ? We : (b == 1) ? W1 : W2;
        unsigned short* D = (b == 0) ? Wep : (b == 1) ? W1p : W2p;
        for (int i = threadIdx.x; i < 18 * 64 * 8; i += blockDim.x) {
            int f = i >> 9, rem = i & 511;
            int l = rem >> 3, j = rem & 7;
            int ot = f / 3, kb = f % 3;
            int o = ot * 16 + (l & 15);
            int k = kb * 32 + ((l >> 4) << 3) + j;
            D[i] = bf16_1(S[o * NF + k]);
        }
    } else {
        int e = (b - 3) * 256 + threadIdx.x;
        if (e < NEDGES) atomicAdd(&deg[ei[NEDGES + e]], 1);
    }
}

// ---------------------------------------------------------------------------
// 2-kernel scan (partial sums; write does local scan of partials) + fill
// ---------------------------------------------------------------------------
#define SCAN_BLOCKS 196  // ceil(50000 / 256)

__global__ __launch_bounds__(256) void scan_partial(const int* __restrict__ deg,
                                                    int* __restrict__ bsum) {
    __shared__ int red[256];
    int t = threadIdx.x;
    int i = blockIdx.x * 256 + t;
    red[t] = (i < NNODES) ? deg[i] : 0;
    __syncthreads();
    for (int off = 128; off; off >>= 1) {
        if (t < off) red[t] += red[t + off];
        __syncthreads();
    }
    if (t == 0) bsum[blockIdx.x] = red[0];
}

__global__ __launch_bounds__(256) void scan_write(const int* __restrict__ deg,
                                                  const int* __restrict__ bsum,
                                                  int* __restrict__ start,
                                                  int* __restrict__ cursor) {
    __shared__ int sb[256];
    __shared__ int s[256];
    int t = threadIdx.x;
    sb[t] = (t < SCAN_BLOCKS) ? bsum[t] : 0;
    __syncthreads();
    for (int off = 1; off < 256; off <<= 1) {
        int v = (t >= off) ? sb[t - off] : 0;
        __syncthreads();
        sb[t] += v;
        __syncthreads();
    }
    int bbase = (blockIdx.x == 0) ? 0 : sb[blockIdx.x - 1];

    int i = blockIdx.x * 256 + t;
    int d = (i < NNODES) ? deg[i] : 0;
    s[t] = d;
    __syncthreads();
    for (int off = 1; off < 256; off <<= 1) {
        int v = (t >= off) ? s[t - off] : 0;
        __syncthreads();
        s[t] += v;
        __syncthreads();
    }
    int excl = ((t == 0) ? 0 : s[t - 1]) + bbase;
    if (i < NNODES) {
        start[i] = excl;
        cursor[i] = excl;
        if (i == NNODES - 1) start[NNODES] = excl + d;
    }
}

// fill: pos[e] = slot (sequential write); ss[slot] = (src, dst) (scatter)
__global__ void fill_kernel(const int* __restrict__ ei, int* __restrict__ cursor,
                            int* __restrict__ pos, int2* __restrict__ ss) {
    int e = blockIdx.x * blockDim.x + threadIdx.x;
    if (e < NEDGES) {
        int d = ei[NEDGES + e];
        int p = atomicAdd(&cursor[d], 1);
        pos[e] = p;
        ss[p] = make_int2(ei[e], d);
    }
}

// ---------------------------------------------------------------------------
// permute_attr: sequential read of attr (f32), bf16-convert, scatter-write
// rows into CSR slot order. Random traffic is WRITE-side (no wave stalls).
// item = e*12 + j; j covers 8 floats -> 8 bf16 (16B write).
// ---------------------------------------------------------------------------
__global__ __launch_bounds__(256) void permute_attr(
    const float* __restrict__ attr, const int* __restrict__ pos,
    unsigned short* __restrict__ ab) {
    const float4* a4 = reinterpret_cast<const float4*>(attr);
    const int stride = gridDim.x * blockDim.x;
    for (int item = blockIdx.x * blockDim.x + threadIdx.x;
         item < NEDGES * 12; item += stride) {
        int e = item / 12, j = item % 12;
        int p = pos[e];
        float4 v0 = a4[e * 24 + j * 2];
        float4 v1 = a4[e * 24 + j * 2 + 1];
        uint4 o = make_uint4(pk_bf16(v0.x, v0.y), pk_bf16(v0.z, v0.w),
                             pk_bf16(v1.x, v1.y), pk_bf16(v1.z, v1.w));
        *reinterpret_cast<uint4*>(ab + (size_t)p * NF + j * 8) = o;
    }
}

// ---------------------------------------------------------------------------
// Fully fused: edge-GEMM + segment-sum + tail node-MLP.
// R16: attr comes from ab (bf16, slot-ordered) -> SEQUENTIAL reads, no eidx,
// no cvt on the A-side. xe dbuf + ss pipeline unchanged from R15.
// ---------------------------------------------------------------------------
__global__ __launch_bounds__(256) void fused_all(
    const unsigned short* __restrict__ ab, const int2* __restrict__ ss_g,
    const int* __restrict__ start, const float* __restrict__ x,
    const unsigned short* __restrict__ Wpack, const float* __restrict__ be,
    const float* __restrict__ epsp,
    const unsigned short* __restrict__ W1p, const float* __restrict__ b1,
    const unsigned short* __restrict__ W2p, const float* __restrict__ b2,
    float* __restrict__ out) {
    __shared__ short Wlds[18 * 64 * 8];               // 18,432 B
    __shared__ float AccT[WPB * NBW * ACC_STRIDE];    //  6,400 B (Acc -> T)
    __shared__ float Ht[16][ACC_STRIDE];              //  6,400 B

    const int t = threadIdx.x;
    {
        const uint4* wsrc = reinterpret_cast<const uint4*>(Wpack);
        uint4* wdst = reinterpret_cast<uint4*>(Wlds);
        for (int i = t; i < 18 * 64; i += 256) wdst[i] = wsrc[i];
        for (int i = t; i < WPB * NBW * ACC_STRIDE; i += 256) AccT[i] = 0.f;
    }
    __syncthreads();

    const int w = t >> 6;
    const int lane = t & 63;
    const int l15 = lane & 15, l4 = lane >> 4;
    const int n0w = (blockIdx.x * WPB + w) * NBW;      // grid exact: < NNODES
    const int s0 = start[n0w], s1 = start[n0w + NBW];
    float* AccW = &AccT[w * NBW * ACC_STRIDE];

    float bias[6];
#pragma unroll
    for (int ot = 0; ot < 6; ++ot) bias[ot] = be[ot * 16 + l15];

    const int nt = (s1 - s0 + 15) >> 4;

    if (nt > 0) {
        const int smax = s1 - 1;

        // ---- prologue: tile 0 attr (seq bf16) + xe + tile 1 indices ----
        bf16x8 a_cur[3];
        float xe_cur[4][6];
        int2 ss_cur[4], ss_nxt[4];
        {
            const unsigned short* ar =
                ab + (size_t)imin(s0 + l15, smax) * NF + l4 * 8;
            a_cur[0] = *reinterpret_cast<const bf16x8*>(ar);
            a_cur[1] = *reinterpret_cast<const bf16x8*>(ar + 32);
            a_cur[2] = *reinterpret_cast<const bf16x8*>(ar + 64);
#pragma unroll
            for (int r = 0; r < 4; ++r) {
                ss_cur[r] = ss_g[imin(s0 + l4 * 4 + r, smax)];
                ss_nxt[r] = ss_g[imin(s0 + 16 + l4 * 4 + r, smax)];
            }
#pragma unroll
            for (int r = 0; r < 4; ++r) {
                const float* xr = x + (size_t)ss_cur[r].x * NF + l15;
#pragma unroll
                for (int ot = 0; ot < 6; ++ot) xe_cur[r][ot] = xr[ot * 16];
            }
        }

        for (int tt = 0; tt < nt; ++tt) {
            const int base = s0 + 16 * tt;

            // ---- 1. copy current A-frags; reissue seq loads for tt+1 ----
            bf16x8 af[3];
            af[0] = a_cur[0]; af[1] = a_cur[1]; af[2] = a_cur[2];
            {
                const unsigned short* ar =
                    ab + (size_t)imin(base + 16 + l15, smax) * NF + l4 * 8;
                a_cur[0] = *reinterpret_cast<const bf16x8*>(ar);
                a_cur[1] = *reinterpret_cast<const bf16x8*>(ar + 32);
                a_cur[2] = *reinterpret_cast<const bf16x8*>(ar + 64);
            }

            // ---- 2. current masks; prefetch xe for tile tt+1 (ss_nxt) ----
            int m[4];
#pragma unroll
            for (int r = 0; r < 4; ++r)
                m[r] = ((base + l4 * 4 + r) < s1) ? (ss_cur[r].y - n0w) : -1;

            float xe_nxt[4][6];
#pragma unroll
            for (int r = 0; r < 4; ++r) {
                const float* xr = x + (size_t)ss_nxt[r].x * NF + l15;
#pragma unroll
                for (int ot = 0; ot < 6; ++ot) xe_nxt[r][ot] = xr[ot * 16];
            }

            // ---- 3. rotate index state; load tile tt+2 indices ----
#pragma unroll
            for (int r = 0; r < 4; ++r) ss_cur[r] = ss_nxt[r];
#pragma unroll
            for (int r = 0; r < 4; ++r)
                ss_nxt[r] = ss_g[imin(base + 32 + l4 * 4 + r, smax)];

            // ---- 4. 18 MFMA: D[e][o] ----
            f32x4 acc[6];
#pragma unroll
            for (int ot = 0; ot < 6; ++ot) {
                f32x4 c = {bias[ot], bias[ot], bias[ot], bias[ot]};
#pragma unroll
                for (int kb = 0; kb < 3; ++kb) {
                    bf16x8 bf = *reinterpret_cast<const bf16x8*>(
                        &Wlds[((ot * 3 + kb) * 64 + lane) * 8]);
                    c = __builtin_amdgcn_mfma_f32_16x16x32_bf16(af[kb], bf, c,
                                                                0, 0, 0);
                }
                acc[ot] = c;
            }

            // ---- 5. epilogue: relu + in-lane segmented reduce + ds_add ----
            const bool c1 = (m[1] == m[0]);
            const bool c2 = (m[2] == m[1]);
            const bool c3 = (m[3] == m[2]);
#pragma unroll
            for (int ot = 0; ot < 6; ++ot) {
                const int o = ot * 16 + l15;
                float v0 = fmaxf(acc[ot][0] + xe_cur[0][ot], 0.f);
                float v1 = fmaxf(acc[ot][1] + xe_cur[1][ot], 0.f);
                float v2 = fmaxf(acc[ot][2] + xe_cur[2][ot], 0.f);
                float v3 = fmaxf(acc[ot][3] + xe_cur[3][ot], 0.f);
                float run = v0;
                if (!c1) {
                    if (m[0] >= 0) atomicAdd(&AccW[m[0] * ACC_STRIDE + o], run);
                    run = 0.f;
                }
                run += v1;
                if (!c2) {
                    if (m[1] >= 0) atomicAdd(&AccW[m[1] * ACC_STRIDE + o], run);
                    run = 0.f;
                }
                run += v2;
                if (!c3) {
                    if (m[2] >= 0) atomicAdd(&AccW[m[2] * ACC_STRIDE + o], run);
                    run = 0.f;
                }
                run += v3;
                if (m[3] >= 0) atomicAdd(&AccW[m[3] * ACC_STRIDE + o], run);
            }

            // ---- 6. rotate xe ----
#pragma unroll
            for (int r = 0; r < 4; ++r)
#pragma unroll
                for (int ot = 0; ot < 6; ++ot) xe_cur[r][ot] = xe_nxt[r][ot];
        }
    }

    // ---- drain this wave's ds_adds; build Ht = (1+eps)x + Acc ----
    asm volatile("s_waitcnt lgkmcnt(0)" ::: "memory");
    __builtin_amdgcn_sched_barrier(0);
    const float ep = 1.0f + *epsp;
#pragma unroll
    for (int i = 0; i < NBW * NF / 64; ++i) {  // 6
        int item = lane + 64 * i;
        int n = item / NF, f = item % NF;
        Ht[w * NBW + n][f] =
            fmaf(ep, x[(size_t)(n0w + n) * NF + f], AccW[n * ACC_STRIDE + f]);
    }
    __syncthreads();   // Ht complete; Acc dead -> AccT becomes T

    // ---- tail MLP for the block's 16 nodes; waves split ot-slices ----
    const int nb0 = blockIdx.x * (WPB * NBW);

    bf16x8 af1[3];
#pragma unroll
    for (int kb = 0; kb < 3; ++kb) {
        const float4* tr = reinterpret_cast<const float4*>(
            &Ht[l15][kb * 32 + l4 * 8]);
        af1[kb] = cvt8(tr[0], tr[1]);
    }
    for (int ot = w; ot < 6; ot += WPB) {
        float b = b1[ot * 16 + l15];
        f32x4 c = {b, b, b, b};
#pragma unroll
        for (int kb = 0; kb < 3; ++kb) {
            bf16x8 bf = *reinterpret_cast<const bf16x8*>(
                W1p + ((ot * 3 + kb) * 64 + lane) * 8);
            c = __builtin_amdgcn_mfma_f32_16x16x32_bf16(af1[kb], bf, c, 0, 0, 0);
        }
#pragma unroll
        for (int r = 0; r < 4; ++r)
            AccT[(l4 * 4 + r) * ACC_STRIDE + ot * 16 + l15] = fmaxf(c[r], 0.f);
    }
    __syncthreads();   // T complete

    bf16x8 af2[3];
#pragma unroll
    for (int kb = 0; kb < 3; ++kb) {
        const float4* tr = reinterpret_cast<const float4*>(
            &AccT[l15 * ACC_STRIDE + kb * 32 + l4 * 8]);
        af2[kb] = cvt8(tr[0], tr[1]);
    }
    for (int ot = w; ot < 6; ot += WPB) {
        float b = b2[ot * 16 + l15];
        f32x4 c = {b, b, b, b};
#pragma unroll
        for (int kb = 0; kb < 3; ++kb) {
            bf16x8 bf = *reinterpret_cast<const bf16x8*>(
                W2p + ((ot * 3 + kb) * 64 + lane) * 8);
            c = __builtin_amdgcn_mfma_f32_16x16x32_bf16(af2[kb], bf, c, 0, 0, 0);
        }
#pragma unroll
        for (int r = 0; r < 4; ++r)
            out[(size_t)(nb0 + l4 * 4 + r) * NF + ot * 16 + l15] = c[r];
    }
}

// ---------------------------------------------------------------------------
extern "C" void kernel_launch(void* const* d_in, const int* in_sizes, int n_in,
                              void* d_out, int out_size, void* d_ws, size_t ws_size,
                              hipStream_t stream) {
    const float* x   = (const float*)d_in[0];
    const int*   ei  = (const int*)d_in[1];
    const float* ea  = (const float*)d_in[2];
    const float* We  = (const float*)d_in[3];
    const float* be  = (const float*)d_in[4];
    const float* eps = (const float*)d_in[5];
    const float* W1  = (const float*)d_in[6];
    const float* b1  = (const float*)d_in[7];
    const float* W2  = (const float*)d_in[8];
    const float* b2  = (const float*)d_in[9];
    float* out = (float*)d_out;

    // ws layout
    unsigned short* Wep = (unsigned short*)d_ws;         // 9216 bf16
    unsigned short* W1p = Wep + 18 * 64 * 8;             // 9216
    unsigned short* W2p = W1p + 18 * 64 * 8;             // 9216
    int* deg    = (int*)(W2p + 18 * 64 * 8);             // 50000
    int* start  = deg + NNODES;                          // 50001
    int* cursor = start + NNODES + 1;                    // 50000
    int* pos    = cursor + NNODES;                       // 800000
    int2* ss    = (int2*)(pos + NEDGES);                 // 800000 int2 (+pad)
    int* bsum   = (int*)(ss + NEDGES + 64);              // 256
    unsigned short* ab = (unsigned short*)(bsum + 256);  // 800016*96 bf16 (154MB)

    hipMemsetAsync(deg, 0, NNODES * sizeof(int), stream);
    prep_hist<<<3 + (NEDGES + 255) / 256, 256, 0, stream>>>(We, W1, W2, Wep, W1p,
                                                            W2p, ei, deg);
    scan_partial<<<SCAN_BLOCKS, 256, 0, stream>>>(deg, bsum);
    scan_write<<<SCAN_BLOCKS, 256, 0, stream>>>(deg, bsum, start, cursor);
    fill_kernel<<<(NEDGES + 255) / 256, 256, 0, stream>>>(ei, cursor, pos, ss);
    permute_attr<<<4096, 256, 0, stream>>>(ea, pos, ab);
    int nblocks = NNODES / (WPB * NBW);                  // 3125 exact
    fused_all<<<nblocks, 256, 0, stream>>>(ab, ss, start, x, Wep, be, eps,
                                           W1p, b1, W2p, b2, out);
}

// Round 17
// 279.500 us; speedup vs baseline: 1.2985x; 1.2985x over previous
//
#include <hip/hip_runtime.h>

#define NNODES 50000
#define NEDGES 800000
#define NF 96
#define NF4 24              // float4 per f32 row
#define NBW 4               // nodes per wave (fused): 12500 waves total
#define WPB 4               // waves per block (256 threads); block owns 16 nodes
#define ACC_STRIDE 100      // Acc/T/Ht row stride (floats, 400B, 16B-aligned)

typedef short bf16x8 __attribute__((ext_vector_type(8)));
typedef float f32x4 __attribute__((ext_vector_type(4)));

__device__ inline unsigned pk_bf16(float a, float b) {
    union { __bf16 h[2]; unsigned u; } q;
    q.h[0] = (__bf16)a; q.h[1] = (__bf16)b;
    return q.u;
}
__device__ inline unsigned short bf16_1(float a) {
    union { __bf16 h; unsigned short u; } q;
    q.h = (__bf16)a;
    return q.u;
}
__device__ inline float bf2f(unsigned u) {
    union { unsigned u; float f; } q;
    q.u = u << 16;
    return q.f;
}
__device__ inline bf16x8 cvt8(float4 a, float4 b) {
    union { unsigned u[4]; bf16x8 v; } q;
    q.u[0] = pk_bf16(a.x, a.y); q.u[1] = pk_bf16(a.z, a.w);
    q.u[2] = pk_bf16(b.x, b.y); q.u[3] = pk_bf16(b.z, b.w);
    return q.v;
}
__device__ inline int imin(int a, int b) { return a < b ? a : b; }

// ---------------------------------------------------------------------------
// prep: blocks 0/1/2 pack We/W1/W2 into MFMA B-fragment order (bf16);
// remaining blocks do the dst histogram.
// ---------------------------------------------------------------------------
__global__ __launch_bounds__(256) void prep_hist(
    const float* __restrict__ We, const float* __restrict__ W1,
    const float* __restrict__ W2, unsigned short* __restrict__ Wep,
    unsigned short* __restrict__ W1p, unsigned short* __restrict__ W2p,
    const int* __restrict__ ei, int* __restrict__ deg) {
    int b = blockIdx.x;
    if (b < 3) {
        const float* S = (b == 0) ? We : (b == 1) ? W1 : W2;
        unsigned short* D = (b == 0) ? Wep : (b == 1) ? W1p : W2p;
        for (int i = threadIdx.x; i < 18 * 64 * 8; i += blockDim.x) {
            int f = i >> 9, rem = i & 511;
            int l = rem >> 3, j = rem & 7;
            int ot = f / 3, kb = f % 3;
            int o = ot * 16 + (l & 15);
            int k = kb * 32 + ((l >> 4) << 3) + j;
            D[i] = bf16_1(S[o * NF + k]);
        }
    } else {
        int e = (b - 3) * 256 + threadIdx.x;
        if (e < NEDGES) atomicAdd(&deg[ei[NEDGES + e]], 1);
    }
}

// ---------------------------------------------------------------------------
// convert_x: x (f32) -> xb (bf16), pure streaming. 29 MB ≈ 6 µs.
// ---------------------------------------------------------------------------
__global__ __launch_bounds__(256) void convert_x(const float* __restrict__ x,
                                                 unsigned* __restrict__ xb32) {
    const float2* x2 = reinterpret_cast<const float2*>(x);
    const int N2 = NNODES * NF / 2;
    for (int i = blockIdx.x * blockDim.x + threadIdx.x; i < N2;
         i += gridDim.x * blockDim.x) {
        float2 v = x2[i];
        xb32[i] = pk_bf16(v.x, v.y);
    }
}

// ---------------------------------------------------------------------------
// 2-kernel scan (partial sums; write does local scan of partials) + fill
// ---------------------------------------------------------------------------
#define SCAN_BLOCKS 196  // ceil(50000 / 256)

__global__ __launch_bounds__(256) void scan_partial(const int* __restrict__ deg,
                                                    int* __restrict__ bsum) {
    __shared__ int red[256];
    int t = threadIdx.x;
    int i = blockIdx.x * 256 + t;
    red[t] = (i < NNODES) ? deg[i] : 0;
    __syncthreads();
    for (int off = 128; off; off >>= 1) {
        if (t < off) red[t] += red[t + off];
        __syncthreads();
    }
    if (t == 0) bsum[blockIdx.x] = red[0];
}

__global__ __launch_bounds__(256) void scan_write(const int* __restrict__ deg,
                                                  const int* __restrict__ bsum,
                                                  int* __restrict__ start,
                                                  int* __restrict__ cursor) {
    __shared__ int sb[256];
    __shared__ int s[256];
    int t = threadIdx.x;
    sb[t] = (t < SCAN_BLOCKS) ? bsum[t] : 0;
    __syncthreads();
    for (int off = 1; off < 256; off <<= 1) {
        int v = (t >= off) ? sb[t - off] : 0;
        __syncthreads();
        sb[t] += v;
        __syncthreads();
    }
    int bbase = (blockIdx.x == 0) ? 0 : sb[blockIdx.x - 1];

    int i = blockIdx.x * 256 + t;
    int d = (i < NNODES) ? deg[i] : 0;
    s[t] = d;
    __syncthreads();
    for (int off = 1; off < 256; off <<= 1) {
        int v = (t >= off) ? s[t - off] : 0;
        __syncthreads();
        s[t] += v;
        __syncthreads();
    }
    int excl = ((t == 0) ? 0 : s[t - 1]) + bbase;
    if (i < NNODES) {
        start[i] = excl;
        cursor[i] = excl;
        if (i == NNODES - 1) start[NNODES] = excl + d;
    }
}

// fill: eidx[p] = edge id; ss[p] = (src, dst) packed
__global__ void fill_kernel(const int* __restrict__ ei, int* __restrict__ cursor,
                            int* __restrict__ eidx, int2* __restrict__ ss) {
    int e = blockIdx.x * blockDim.x + threadIdx.x;
    if (e < NEDGES) {
        int d = ei[NEDGES + e];
        int p = atomicAdd(&cursor[d], 1);
        eidx[p] = e;
        ss[p] = make_int2(ei[e], d);
    }
}

// ---------------------------------------------------------------------------
// Fully fused: edge-GEMM + segment-sum + tail node-MLP (R15 structure).
// R17 delta: xe gathers read bf16 x (xb) — half bytes, 2x better L2
// residency on the latency-critical x path. Convert at use (u<<16).
// ---------------------------------------------------------------------------
__global__ __launch_bounds__(256) void fused_all(
    const float* __restrict__ attr, const int* __restrict__ eidx,
    const int2* __restrict__ ss_g, const int* __restrict__ start,
    const float* __restrict__ x, const unsigned short* __restrict__ xb,
    const unsigned short* __restrict__ Wpack, const float* __restrict__ be,
    const float* __restrict__ epsp,
    const unsigned short* __restrict__ W1p, const float* __restrict__ b1,
    const unsigned short* __restrict__ W2p, const float* __restrict__ b2,
    float* __restrict__ out) {
    __shared__ short Wlds[18 * 64 * 8];               // 18,432 B
    __shared__ float AccT[WPB * NBW * ACC_STRIDE];    //  6,400 B (Acc -> T)
    __shared__ float Ht[16][ACC_STRIDE];              //  6,400 B

    const int t = threadIdx.x;
    {
        const uint4* wsrc = reinterpret_cast<const uint4*>(Wpack);
        uint4* wdst = reinterpret_cast<uint4*>(Wlds);
        for (int i = t; i < 18 * 64; i += 256) wdst[i] = wsrc[i];
        for (int i = t; i < WPB * NBW * ACC_STRIDE; i += 256) AccT[i] = 0.f;
    }
    __syncthreads();

    const int w = t >> 6;
    const int lane = t & 63;
    const int l15 = lane & 15, l4 = lane >> 4;
    const int n0w = (blockIdx.x * WPB + w) * NBW;      // grid exact: < NNODES
    const int s0 = start[n0w], s1 = start[n0w + NBW];
    float* AccW = &AccT[w * NBW * ACC_STRIDE];

    float bias[6];
#pragma unroll
    for (int ot = 0; ot < 6; ++ot) bias[ot] = be[ot * 16 + l15];

    const float4* a4 = reinterpret_cast<const float4*>(attr);
    const int nt = (s1 - s0 + 15) >> 4;

    if (nt > 0) {
        const int smax = s1 - 1;

        // ---- prologue: tile 0 data (attr + xe) + tile 1 indices ----
        float4 a_cur[6];
        unsigned xe_cur[4][6];
        int2 ss_cur[4], ss_nxt[4];
        int ev_nxt;
        {
            int ev0 = eidx[imin(s0 + l15, smax)];
            const float4* ar = a4 + (size_t)ev0 * NF4 + l4 * 2;
            a_cur[0] = ar[0];  a_cur[1] = ar[1];
            a_cur[2] = ar[8];  a_cur[3] = ar[9];
            a_cur[4] = ar[16]; a_cur[5] = ar[17];
            ev_nxt = eidx[imin(s0 + 16 + l15, smax)];
#pragma unroll
            for (int r = 0; r < 4; ++r) {
                ss_cur[r] = ss_g[imin(s0 + l4 * 4 + r, smax)];
                ss_nxt[r] = ss_g[imin(s0 + 16 + l4 * 4 + r, smax)];
            }
#pragma unroll
            for (int r = 0; r < 4; ++r) {
                const unsigned short* xr = xb + (size_t)ss_cur[r].x * NF + l15;
#pragma unroll
                for (int ot = 0; ot < 6; ++ot) xe_cur[r][ot] = xr[ot * 16];
            }
        }

        for (int tt = 0; tt < nt; ++tt) {
            const int base = s0 + 16 * tt;

            bf16x8 af[3];
            af[0] = cvt8(a_cur[0], a_cur[1]);
            af[1] = cvt8(a_cur[2], a_cur[3]);
            af[2] = cvt8(a_cur[4], a_cur[5]);

            {
                const float4* ar = a4 + (size_t)ev_nxt * NF4 + l4 * 2;
                a_cur[0] = ar[0];  a_cur[1] = ar[1];
                a_cur[2] = ar[8];  a_cur[3] = ar[9];
                a_cur[4] = ar[16]; a_cur[5] = ar[17];
            }
            ev_nxt = eidx[imin(base + 32 + l15, smax)];

            int m[4];
#pragma unroll
            for (int r = 0; r < 4; ++r)
                m[r] = ((base + l4 * 4 + r) < s1) ? (ss_cur[r].y - n0w) : -1;

            unsigned xe_nxt[4][6];
#pragma unroll
            for (int r = 0; r < 4; ++r) {
                const unsigned short* xr = xb + (size_t)ss_nxt[r].x * NF + l15;
#pragma unroll
                for (int ot = 0; ot < 6; ++ot) xe_nxt[r][ot] = xr[ot * 16];
            }

#pragma unroll
            for (int r = 0; r < 4; ++r) ss_cur[r] = ss_nxt[r];
#pragma unroll
            for (int r = 0; r < 4; ++r)
                ss_nxt[r] = ss_g[imin(base + 32 + l4 * 4 + r, smax)];

            f32x4 acc[6];
#pragma unroll
            for (int ot = 0; ot < 6; ++ot) {
                f32x4 c = {bias[ot], bias[ot], bias[ot], bias[ot]};
#pragma unroll
                for (int kb = 0; kb < 3; ++kb) {
                    bf16x8 bf = *reinterpret_cast<const bf16x8*>(
                        &Wlds[((ot * 3 + kb) * 64 + lane) * 8]);
                    c = __builtin_amdgcn_mfma_f32_16x16x32_bf16(af[kb], bf, c,
                                                                0, 0, 0);
                }
                acc[ot] = c;
            }

            const bool c1 = (m[1] == m[0]);
            const bool c2 = (m[2] == m[1]);
            const bool c3 = (m[3] == m[2]);
#pragma unroll
            for (int ot = 0; ot < 6; ++ot) {
                const int o = ot * 16 + l15;
                float v0 = fmaxf(acc[ot][0] + bf2f(xe_cur[0][ot]), 0.f);
                float v1 = fmaxf(acc[ot][1] + bf2f(xe_cur[1][ot]), 0.f);
                float v2 = fmaxf(acc[ot][2] + bf2f(xe_cur[2][ot]), 0.f);
                float v3 = fmaxf(acc[ot][3] + bf2f(xe_cur[3][ot]), 0.f);
                float run = v0;
                if (!c1) {
                    if (m[0] >= 0) atomicAdd(&AccW[m[0] * ACC_STRIDE + o], run);
                    run = 0.f;
                }
                run += v1;
                if (!c2) {
                    if (m[1] >= 0) atomicAdd(&AccW[m[1] * ACC_STRIDE + o], run);
                    run = 0.f;
                }
                run += v2;
                if (!c3) {
                    if (m[2] >= 0) atomicAdd(&AccW[m[2] * ACC_STRIDE + o], run);
                    run = 0.f;
                }
                run += v3;
                if (m[3] >= 0) atomicAdd(&AccW[m[3] * ACC_STRIDE + o], run);
            }

#pragma unroll
            for (int r = 0; r < 4; ++r)
#pragma unroll
                for (int ot = 0; ot < 6; ++ot) xe_cur[r][ot] = xe_nxt[r][ot];
        }
    }

    // ---- drain this wave's ds_adds; build Ht = (1+eps)x + Acc (fp32 x) ----
    asm volatile("s_waitcnt lgkmcnt(0)" ::: "memory");
    __builtin_amdgcn_sched_barrier(0);
    const float ep = 1.0f + *epsp;
#pragma unroll
    for (int i = 0; i < NBW * NF / 64; ++i) {  // 6
        int item = lane + 64 * i;
        int n = item / NF, f = item % NF;
        Ht[w * NBW + n][f] =
            fmaf(ep, x[(size_t)(n0w + n) * NF + f], AccW[n * ACC_STRIDE + f]);
    }
    __syncthreads();   // Ht complete; Acc dead -> AccT becomes T

    // ---- tail MLP for the block's 16 nodes; waves split ot-slices ----
    const int nb0 = blockIdx.x * (WPB * NBW);

    bf16x8 af1[3];
#pragma unroll
    for (int kb = 0; kb < 3; ++kb) {
        const float4* tr = reinterpret_cast<const float4*>(
            &Ht[l15][kb * 32 + l4 * 8]);
        af1[kb] = cvt8(tr[0], tr[1]);
    }
    for (int ot = w; ot < 6; ot += WPB) {
        float b = b1[ot * 16 + l15];
        f32x4 c = {b, b, b, b};
#pragma unroll
        for (int kb = 0; kb < 3; ++kb) {
            bf16x8 bf = *reinterpret_cast<const bf16x8*>(
                W1p + ((ot * 3 + kb) * 64 + lane) * 8);
            c = __builtin_amdgcn_mfma_f32_16x16x32_bf16(af1[kb], bf, c, 0, 0, 0);
        }
#pragma unroll
        for (int r = 0; r < 4; ++r)
            AccT[(l4 * 4 + r) * ACC_STRIDE + ot * 16 + l15] = fmaxf(c[r], 0.f);
    }
    __syncthreads();   // T complete

    bf16x8 af2[3];
#pragma unroll
    for (int kb = 0; kb < 3; ++kb) {
        const float4* tr = reinterpret_cast<const float4*>(
            &AccT[l15 * ACC_STRIDE + kb * 32 + l4 * 8]);
        af2[kb] = cvt8(tr[0], tr[1]);
    }
    for (int ot = w; ot < 6; ot += WPB) {
        float b = b2[ot * 16 + l15];
        f32x4 c = {b, b, b, b};
#pragma unroll
        for (int kb = 0; kb < 3; ++kb) {
            bf16x8 bf = *reinterpret_cast<const bf16x8*>(
                W2p + ((ot * 3 + kb) * 64 + lane) * 8);
            c = __builtin_amdgcn_mfma_f32_16x16x32_bf16(af2[kb], bf, c, 0, 0, 0);
        }
#pragma unroll
        for (int r = 0; r < 4; ++r)
            out[(size_t)(nb0 + l4 * 4 + r) * NF + ot * 16 + l15] = c[r];
    }
}

// ---------------------------------------------------------------------------
extern "C" void kernel_launch(void* const* d_in, const int* in_sizes, int n_in,
                              void* d_out, int out_size, void* d_ws, size_t ws_size,
                              hipStream_t stream) {
    const float* x   = (const float*)d_in[0];
    const int*   ei  = (const int*)d_in[1];
    const float* ea  = (const float*)d_in[2];
    const float* We  = (const float*)d_in[3];
    const float* be  = (const float*)d_in[4];
    const float* eps = (const float*)d_in[5];
    const float* W1  = (const float*)d_in[6];
    const float* b1  = (const float*)d_in[7];
    const float* W2  = (const float*)d_in[8];
    const float* b2  = (const float*)d_in[9];
    float* out = (float*)d_out;

    // ws layout
    unsigned short* Wep = (unsigned short*)d_ws;         // 9216 bf16
    unsigned short* W1p = Wep + 18 * 64 * 8;             // 9216
    unsigned short* W2p = W1p + 18 * 64 * 8;             // 9216
    unsigned short* xb  = W2p + 18 * 64 * 8;             // 50000*96 bf16 (9.6MB)
    int* deg    = (int*)(xb + (size_t)NNODES * NF);      // 50000
    int* start  = deg + NNODES;                          // 50001
    int* cursor = start + NNODES + 1;                    // 50000
    int* eidx   = cursor + NNODES;                       // 800000 (+pad)
    int2* ss    = (int2*)(eidx + NEDGES + 64);           // 800000 int2 (+pad)
    int* bsum   = (int*)(ss + NEDGES + 64);              // 256

    hipMemsetAsync(deg, 0, NNODES * sizeof(int), stream);
    prep_hist<<<3 + (NEDGES + 255) / 256, 256, 0, stream>>>(We, W1, W2, Wep, W1p,
                                                            W2p, ei, deg);
    convert_x<<<1024, 256, 0, stream>>>(x, (unsigned*)xb);
    scan_partial<<<SCAN_BLOCKS, 256, 0, stream>>>(deg, bsum);
    scan_write<<<SCAN_BLOCKS, 256, 0, stream>>>(deg, bsum, start, cursor);
    fill_kernel<<<(NEDGES + 255) / 256, 256, 0, stream>>>(ei, cursor, eidx, ss);
    int nblocks = NNODES / (WPB * NBW);                  // 3125 exact
    fused_all<<<nblocks, 256, 0, stream>>>(ea, eidx, ss, start, x, xb, Wep, be,
                                           eps, W1p, b1, W2p, b2, out);
}

// Round 18
// 272.116 us; speedup vs baseline: 1.3337x; 1.0271x over previous
//
#include <hip/hip_runtime.h>

#define NNODES 50000
#define NEDGES 800000
#define NF 96
#define NF4 24              // float4 per f32 row
#define NBW 4               // nodes per wave (fused): 12500 waves total
#define WPB 4               // waves per block (256 threads); block owns 16 nodes
#define ACC_STRIDE 100      // Acc/T/Ht row stride (floats, 400B, 16B-aligned)

typedef short bf16x8 __attribute__((ext_vector_type(8)));
typedef float f32x4 __attribute__((ext_vector_type(4)));

__device__ inline unsigned pk_bf16(float a, float b) {
    union { __bf16 h[2]; unsigned u; } q;
    q.h[0] = (__bf16)a; q.h[1] = (__bf16)b;
    return q.u;
}
__device__ inline unsigned short bf16_1(float a) {
    union { __bf16 h; unsigned short u; } q;
    q.h = (__bf16)a;
    return q.u;
}
__device__ inline float bf2f_lo(unsigned u) {
    union { unsigned u; float f; } q;
    q.u = u << 16;
    return q.f;
}
__device__ inline float bf2f_hi(unsigned u) {
    union { unsigned u; float f; } q;
    q.u = u & 0xffff0000u;
    return q.f;
}
__device__ inline bf16x8 cvt8(float4 a, float4 b) {
    union { unsigned u[4]; bf16x8 v; } q;
    q.u[0] = pk_bf16(a.x, a.y); q.u[1] = pk_bf16(a.z, a.w);
    q.u[2] = pk_bf16(b.x, b.y); q.u[3] = pk_bf16(b.z, b.w);
    return q.v;
}
__device__ inline int imin(int a, int b) { return a < b ? a : b; }

#define HISTB ((NEDGES + 255) / 256)        // 3125
#define XPERMB ((NNODES * 48 + 255) / 256)  // 9375

// ---------------------------------------------------------------------------
// prep: b<3 pack We/W1/W2 into MFMA B-fragment order (bf16);
// b in [3, 3+HISTB): dst histogram; rest: x -> xb2 gather-friendly bf16 perm.
// xb2 u32 word (n*48 + l15*3 + j) = pk_bf16(x[n][32j+l15], x[n][32j+16+l15])
// ---------------------------------------------------------------------------
__global__ __launch_bounds__(256) void prep_hist(
    const float* __restrict__ We, const float* __restrict__ W1,
    const float* __restrict__ W2, unsigned short* __restrict__ Wep,
    unsigned short* __restrict__ W1p, unsigned short* __restrict__ W2p,
    const int* __restrict__ ei, int* __restrict__ deg,
    const float* __restrict__ x, unsigned* __restrict__ xb2) {
    int b = blockIdx.x;
    if (b < 3) {
        const float* S = (b == 0) ? We : (b == 1) ? W1 : W2;
        unsigned short* D = (b == 0) ? Wep : (b == 1) ? W1p : W2p;
        for (int i = threadIdx.x; i < 18 * 64 * 8; i += blockDim.x) {
            int f = i >> 9, rem = i & 511;
            int l = rem >> 3, j = rem & 7;
            int ot = f / 3, kb = f % 3;
            int o = ot * 16 + (l & 15);
            int k = kb * 32 + ((l >> 4) << 3) + j;
            D[i] = bf16_1(S[o * NF + k]);
        }
    } else if (b < 3 + HISTB) {
        int e = (b - 3) * 256 + threadIdx.x;
        if (e < NEDGES) atomicAdd(&deg[ei[NEDGES + e]], 1);
    } else {
        int item = (b - 3 - HISTB) * 256 + threadIdx.x;
        if (item < NNODES * 48) {
            int n = item / 48, rem = item % 48;
            int l15 = rem / 3, j = rem % 3;
            const float* xr = x + (size_t)n * NF;
            xb2[(size_t)n * 48 + l15 * 3 + j] =
                pk_bf16(xr[32 * j + l15], xr[32 * j + 16 + l15]);
        }
    }
}

// ---------------------------------------------------------------------------
// 2-kernel scan (partial sums; write does local scan of partials) + fill
// ---------------------------------------------------------------------------
#define SCAN_BLOCKS 196  // ceil(50000 / 256)

__global__ __launch_bounds__(256) void scan_partial(const int* __restrict__ deg,
                                                    int* __restrict__ bsum) {
    __shared__ int red[256];
    int t = threadIdx.x;
    int i = blockIdx.x * 256 + t;
    red[t] = (i < NNODES) ? deg[i] : 0;
    __syncthreads();
    for (int off = 128; off; off >>= 1) {
        if (t < off) red[t] += red[t + off];
        __syncthreads();
    }
    if (t == 0) bsum[blockIdx.x] = red[0];
}

__global__ __launch_bounds__(256) void scan_write(const int* __restrict__ deg,
                                                  const int* __restrict__ bsum,
                                                  int* __restrict__ start,
                                                  int* __restrict__ cursor) {
    __shared__ int sb[256];
    __shared__ int s[256];
    int t = threadIdx.x;
    sb[t] = (t < SCAN_BLOCKS) ? bsum[t] : 0;
    __syncthreads();
    for (int off = 1; off < 256; off <<= 1) {
        int v = (t >= off) ? sb[t - off] : 0;
        __syncthreads();
        sb[t] += v;
        __syncthreads();
    }
    int bbase = (blockIdx.x == 0) ? 0 : sb[blockIdx.x - 1];

    int i = blockIdx.x * 256 + t;
    int d = (i < NNODES) ? deg[i] : 0;
    s[t] = d;
    __syncthreads();
    for (int off = 1; off < 256; off <<= 1) {
        int v = (t >= off) ? s[t - off] : 0;
        __syncthreads();
        s[t] += v;
        __syncthreads();
    }
    int excl = ((t == 0) ? 0 : s[t - 1]) + bbase;
    if (i < NNODES) {
        start[i] = excl;
        cursor[i] = excl;
        if (i == NNODES - 1) start[NNODES] = excl + d;
    }
}

// fill: eidx[p] = edge id; ss[p] = (src, dst) packed
__global__ void fill_kernel(const int* __restrict__ ei, int* __restrict__ cursor,
                            int* __restrict__ eidx, int2* __restrict__ ss) {
    int e = blockIdx.x * blockDim.x + threadIdx.x;
    if (e < NEDGES) {
        int d = ei[NEDGES + e];
        int p = atomicAdd(&cursor[d], 1);
        eidx[p] = e;
        ss[p] = make_int2(ei[e], d);
    }
}

// ---------------------------------------------------------------------------
// Fully fused: edge-GEMM + segment-sum + tail node-MLP (R15 structure).
// R18 delta: x gathers read xb2 (gather-friendly bf16 layout) — ONE 16B load
// per (lane, edge) instead of 6 strided scalars: 24 -> 4 requests/lane/tile.
// ---------------------------------------------------------------------------
__global__ __launch_bounds__(256) void fused_all(
    const float* __restrict__ attr, const int* __restrict__ eidx,
    const int2* __restrict__ ss_g, const int* __restrict__ start,
    const float* __restrict__ x, const unsigned* __restrict__ xb2,
    const unsigned short* __restrict__ Wpack, const float* __restrict__ be,
    const float* __restrict__ epsp,
    const unsigned short* __restrict__ W1p, const float* __restrict__ b1,
    const unsigned short* __restrict__ W2p, const float* __restrict__ b2,
    float* __restrict__ out) {
    __shared__ short Wlds[18 * 64 * 8];               // 18,432 B
    __shared__ float AccT[WPB * NBW * ACC_STRIDE];    //  6,400 B (Acc -> T)
    __shared__ float Ht[16][ACC_STRIDE];              //  6,400 B

    const int t = threadIdx.x;
    {
        const uint4* wsrc = reinterpret_cast<const uint4*>(Wpack);
        uint4* wdst = reinterpret_cast<uint4*>(Wlds);
        for (int i = t; i < 18 * 64; i += 256) wdst[i] = wsrc[i];
        for (int i = t; i < WPB * NBW * ACC_STRIDE; i += 256) AccT[i] = 0.f;
    }
    __syncthreads();

    const int w = t >> 6;
    const int lane = t & 63;
    const int l15 = lane & 15, l4 = lane >> 4;
    const int n0w = (blockIdx.x * WPB + w) * NBW;      // grid exact: < NNODES
    const int s0 = start[n0w], s1 = start[n0w + NBW];
    float* AccW = &AccT[w * NBW * ACC_STRIDE];

    float bias[6];
#pragma unroll
    for (int ot = 0; ot < 6; ++ot) bias[ot] = be[ot * 16 + l15];

    const float4* a4 = reinterpret_cast<const float4*>(attr);
    const int l15x3 = l15 * 3;
    const int nt = (s1 - s0 + 15) >> 4;

    if (nt > 0) {
        const int smax = s1 - 1;

        // ---- prologue: tile 0 data (attr + xe) + tile 1 indices ----
        float4 a_cur[6];
        uint4 xe_cur[4];              // words 0..2 = bf16 pairs (ot 0/1,2/3,4/5)
        int2 ss_cur[4], ss_nxt[4];
        int ev_nxt;
        {
            int ev0 = eidx[imin(s0 + l15, smax)];
            const float4* ar = a4 + (size_t)ev0 * NF4 + l4 * 2;
            a_cur[0] = ar[0];  a_cur[1] = ar[1];
            a_cur[2] = ar[8];  a_cur[3] = ar[9];
            a_cur[4] = ar[16]; a_cur[5] = ar[17];
            ev_nxt = eidx[imin(s0 + 16 + l15, smax)];
#pragma unroll
            for (int r = 0; r < 4; ++r) {
                ss_cur[r] = ss_g[imin(s0 + l4 * 4 + r, smax)];
                ss_nxt[r] = ss_g[imin(s0 + 16 + l4 * 4 + r, smax)];
            }
#pragma unroll
            for (int r = 0; r < 4; ++r)
                xe_cur[r] = *reinterpret_cast<const uint4*>(
                    xb2 + (size_t)ss_cur[r].x * 48 + l15x3);
        }

        for (int tt = 0; tt < nt; ++tt) {
            const int base = s0 + 16 * tt;

            bf16x8 af[3];
            af[0] = cvt8(a_cur[0], a_cur[1]);
            af[1] = cvt8(a_cur[2], a_cur[3]);
            af[2] = cvt8(a_cur[4], a_cur[5]);

            {
                const float4* ar = a4 + (size_t)ev_nxt * NF4 + l4 * 2;
                a_cur[0] = ar[0];  a_cur[1] = ar[1];
                a_cur[2] = ar[8];  a_cur[3] = ar[9];
                a_cur[4] = ar[16]; a_cur[5] = ar[17];
            }
            ev_nxt = eidx[imin(base + 32 + l15, smax)];

            int m[4];
#pragma unroll
            for (int r = 0; r < 4; ++r)
                m[r] = ((base + l4 * 4 + r) < s1) ? (ss_cur[r].y - n0w) : -1;

            // prefetch xe for tile tt+1 (one 16B load per r)
            uint4 xe_nxt[4];
#pragma unroll
            for (int r = 0; r < 4; ++r)
                xe_nxt[r] = *reinterpret_cast<const uint4*>(
                    xb2 + (size_t)ss_nxt[r].x * 48 + l15x3);

#pragma unroll
            for (int r = 0; r < 4; ++r) ss_cur[r] = ss_nxt[r];
#pragma unroll
            for (int r = 0; r < 4; ++r)
                ss_nxt[r] = ss_g[imin(base + 32 + l4 * 4 + r, smax)];

            f32x4 acc[6];
#pragma unroll
            for (int ot = 0; ot < 6; ++ot) {
                f32x4 c = {bias[ot], bias[ot], bias[ot], bias[ot]};
#pragma unroll
                for (int kb = 0; kb < 3; ++kb) {
                    bf16x8 bf = *reinterpret_cast<const bf16x8*>(
                        &Wlds[((ot * 3 + kb) * 64 + lane) * 8]);
                    c = __builtin_amdgcn_mfma_f32_16x16x32_bf16(af[kb], bf, c,
                                                                0, 0, 0);
                }
                acc[ot] = c;
            }

            const bool c1 = (m[1] == m[0]);
            const bool c2 = (m[2] == m[1]);
            const bool c3 = (m[3] == m[2]);
#pragma unroll
            for (int ot = 0; ot < 6; ++ot) {
                const int o = ot * 16 + l15;
                const int j = ot >> 1;
                const bool hi = ot & 1;
                float x0 = hi ? bf2f_hi(xe_cur[0][j]) : bf2f_lo(xe_cur[0][j]);
                float x1 = hi ? bf2f_hi(xe_cur[1][j]) : bf2f_lo(xe_cur[1][j]);
                float x2 = hi ? bf2f_hi(xe_cur[2][j]) : bf2f_lo(xe_cur[2][j]);
                float x3 = hi ? bf2f_hi(xe_cur[3][j]) : bf2f_lo(xe_cur[3][j]);
                float v0 = fmaxf(acc[ot][0] + x0, 0.f);
                float v1 = fmaxf(acc[ot][1] + x1, 0.f);
                float v2 = fmaxf(acc[ot][2] + x2, 0.f);
                float v3 = fmaxf(acc[ot][3] + x3, 0.f);
                float run = v0;
                if (!c1) {
                    if (m[0] >= 0) atomicAdd(&AccW[m[0] * ACC_STRIDE + o], run);
                    run = 0.f;
                }
                run += v1;
                if (!c2) {
                    if (m[1] >= 0) atomicAdd(&AccW[m[1] * ACC_STRIDE + o], run);
                    run = 0.f;
                }
                run += v2;
                if (!c3) {
                    if (m[2] >= 0) atomicAdd(&AccW[m[2] * ACC_STRIDE + o], run);
                    run = 0.f;
                }
                run += v3;
                if (m[3] >= 0) atomicAdd(&AccW[m[3] * ACC_STRIDE + o], run);
            }

#pragma unroll
            for (int r = 0; r < 4; ++r) xe_cur[r] = xe_nxt[r];
        }
    }

    // ---- drain this wave's ds_adds; build Ht = (1+eps)x + Acc (fp32 x) ----
    asm volatile("s_waitcnt lgkmcnt(0)" ::: "memory");
    __builtin_amdgcn_sched_barrier(0);
    const float ep = 1.0f + *epsp;
#pragma unroll
    for (int i = 0; i < NBW * NF / 64; ++i) {  // 6
        int item = lane + 64 * i;
        int n = item / NF, f = item % NF;
        Ht[w * NBW + n][f] =
            fmaf(ep, x[(size_t)(n0w + n) * NF + f], AccW[n * ACC_STRIDE + f]);
    }
    __syncthreads();   // Ht complete; Acc dead -> AccT becomes T

    // ---- tail MLP for the block's 16 nodes; waves split ot-slices ----
    const int nb0 = blockIdx.x * (WPB * NBW);

    bf16x8 af1[3];
#pragma unroll
    for (int kb = 0; kb < 3; ++kb) {
        const float4* tr = reinterpret_cast<const float4*>(
            &Ht[l15][kb * 32 + l4 * 8]);
        af1[kb] = cvt8(tr[0], tr[1]);
    }
    for (int ot = w; ot < 6; ot += WPB) {
        float b = b1[ot * 16 + l15];
        f32x4 c = {b, b, b, b};
#pragma unroll
        for (int kb = 0; kb < 3; ++kb) {
            bf16x8 bf = *reinterpret_cast<const bf16x8*>(
                W1p + ((ot * 3 + kb) * 64 + lane) * 8);
            c = __builtin_amdgcn_mfma_f32_16x16x32_bf16(af1[kb], bf, c, 0, 0, 0);
        }
#pragma unroll
        for (int r = 0; r < 4; ++r)
            AccT[(l4 * 4 + r) * ACC_STRIDE + ot * 16 + l15] = fmaxf(c[r], 0.f);
    }
    __syncthreads();   // T complete

    bf16x8 af2[3];
#pragma unroll
    for (int kb = 0; kb < 3; ++kb) {
        const float4* tr = reinterpret_cast<const float4*>(
            &AccT[l15 * ACC_STRIDE + kb * 32 + l4 * 8]);
        af2[kb] = cvt8(tr[0], tr[1]);
    }
    for (int ot = w; ot < 6; ot += WPB) {
        float b = b2[ot * 16 + l15];
        f32x4 c = {b, b, b, b};
#pragma unroll
        for (int kb = 0; kb < 3; ++kb) {
            bf16x8 bf = *reinterpret_cast<const bf16x8*>(
                W2p + ((ot * 3 + kb) * 64 + lane) * 8);
            c = __builtin_amdgcn_mfma_f32_16x16x32_bf16(af2[kb], bf, c, 0, 0, 0);
        }
#pragma unroll
        for (int r = 0; r < 4; ++r)
            out[(size_t)(nb0 + l4 * 4 + r) * NF + ot * 16 + l15] = c[r];
    }
}

// ---------------------------------------------------------------------------
extern "C" void kernel_launch(void* const* d_in, const int* in_sizes, int n_in,
                              void* d_out, int out_size, void* d_ws, size_t ws_size,
                              hipStream_t stream) {
    const float* x   = (const float*)d_in[0];
    const int*   ei  = (const int*)d_in[1];
    const float* ea  = (const float*)d_in[2];
    const float* We  = (const float*)d_in[3];
    const float* be  = (const float*)d_in[4];
    const float* eps = (const float*)d_in[5];
    const float* W1  = (const float*)d_in[6];
    const float* b1  = (const float*)d_in[7];
    const float* W2  = (const float*)d_in[8];
    const float* b2  = (const float*)d_in[9];
    float* out = (float*)d_out;

    // ws layout
    unsigned short* Wep = (unsigned short*)d_ws;         // 9216 bf16
    unsigned short* W1p = Wep + 18 * 64 * 8;             // 9216
    unsigned short* W2p = W1p + 18 * 64 * 8;             // 9216
    unsigned* xb2 = (unsigned*)(W2p + 18 * 64 * 8);      // 50000*48 u32 + pad
    int* deg    = (int*)(xb2 + (size_t)NNODES * 48 + 16);// 50000
    int* start  = deg + NNODES;                          // 50001
    int* cursor = start + NNODES + 1;                    // 50000
    int* eidx   = cursor + NNODES;                       // 800000 (+pad)
    int2* ss    = (int2*)(eidx + NEDGES + 64);           // 800000 int2 (+pad)
    int* bsum   = (int*)(ss + NEDGES + 64);              // 256

    hipMemsetAsync(deg, 0, NNODES * sizeof(int), stream);
    prep_hist<<<3 + HISTB + XPERMB, 256, 0, stream>>>(We, W1, W2, Wep, W1p, W2p,
                                                      ei, deg, x, xb2);
    scan_partial<<<SCAN_BLOCKS, 256, 0, stream>>>(deg, bsum);
    scan_write<<<SCAN_BLOCKS, 256, 0, stream>>>(deg, bsum, start, cursor);
    fill_kernel<<<(NEDGES + 255) / 256, 256, 0, stream>>>(ei, cursor, eidx, ss);
    int nblocks = NNODES / (WPB * NBW);                  // 3125 exact
    fused_all<<<nblocks, 256, 0, stream>>>(ea, eidx, ss, start, x, xb2, Wep, be,
                                           eps, W1p, b1, W2p, b2, out);
}